// Round 16
// baseline (24.083 us; speedup 1.0000x reference)
//
#include <hip/hip_runtime.h>
#include <hip/hip_bf16.h>

#define N_X    65536
#define N_IND  1024
#define N_DESC 64
#define STRIPS 16                 // 16-col x-strips per block (256 cols)
#define L2E    1.4426950408889634f
#define L2E2   2.8853900817779268f
#define SKIP_THR (-60.0f)         // 2^-60 * 1024 * |alpha| ~ 4e-15 << tol

typedef __attribute__((ext_vector_type(8))) short  short8;
typedef __attribute__((ext_vector_type(4))) float  f32x4;
typedef __attribute__((ext_vector_type(2))) float  f32x2;

static __device__ __forceinline__ ushort f2bf(float f) {
    union { float f; unsigned u; } a; a.f = f;
    unsigned r = a.u + 0x7FFF + ((a.u >> 16) & 1);   // RNE to bf16
    return (ushort)(r >> 16);
}
static __device__ __forceinline__ float bf2f(ushort h) {
    union { unsigned u; float f; } a; a.u = (unsigned)h << 16;
    return a.f;
}

// ---------------------------------------------------------------------------
// Round 16: INVERTED PLACEMENT. The LDS-read-bound loop (R13-R15 evidence)
// came from every wave re-reading the shared 128 KB z-panel (2 MB/CU/pass).
// Now: each of the 16 waves holds its OWN 64 z-rows in VGPRs (4 tiles x 2
// K-frags = 32 VGPR, loaded once from L2-resident z), and the CONVERTED
// x-panel (256 cols -> 32 KB bf16, XOR-swizzled) is the shared LDS object:
// per-CU LDS flow drops to 16 waves x 32 KB = 512 KB (+ xs2 broadcasts).
// Orientation = R10/R11's verified swap: mfma(A=x_frag, B=z_frag), D row =
// x-col (4g+reg), D col = z-row (p). z2/alpha/zm are lane-local registers;
// the skip test is EXACT per lane; common path does NO accumulation at all.
// Kept contributions (never taken for this data) shfl-reduce over p and add
// into per-wave LDS slots colPart[16][256]; final pass sums 16 slots -> out.
// Swizzle: byte ^= ((col&7)<<4) on BOTH x-panel write and read (rule #21).
// ---------------------------------------------------------------------------
__global__ __launch_bounds__(1024) void igpr_fused(
        const float* __restrict__ x, const float* __restrict__ z,
        const float* __restrict__ alpha, const float* __restrict__ ls,
        float* __restrict__ out) {
    struct SM {
        uint4 xt[256 * 8];        // 256 cols * 128 B = 32 KB (swizzled bf16)
        float xs2[256];           // per-col log2e*||xw||^2
        float colPart[16][256];   // per-wave kept-path partials (16 KB)
    };
    __shared__ SM sm;             // ~49 KB

    const int tid  = threadIdx.x;
    const int lane = tid & 63;
    const int wave = tid >> 6;                 // 0..15: owns z-rows wave*64..
    const int p = lane & 15;                   // z-row within tile (D col)
    const int g = lane >> 4;                   // k-group; D rows 4g..4g+3
    const int jb = blockIdx.x * 256;           // block's first x column

    // ---- zero colPart (4 floats per thread) ----
    {
        float4 zz = {0.f, 0.f, 0.f, 0.f};
        *reinterpret_cast<float4*>(&sm.colPart[0][0] + 4 * tid) = zz;
    }

    // ---- stage x-panel: thread handles col = tid>>2, k-quarter q = tid&3 ----
    {
        const int col = tid >> 2, q = tid & 3;
        float wq[16];
#pragma unroll
        for (int e = 0; e < 16; ++e) wq[e] = __expf(-0.5f * ls[q * 16 + e]);
        const float* xr = x + (size_t)(jb + col) * N_DESC + q * 16;
        float4 v0 = *reinterpret_cast<const float4*>(xr);
        float4 v1 = *reinterpret_cast<const float4*>(xr + 4);
        float4 v2 = *reinterpret_cast<const float4*>(xr + 8);
        float4 v3 = *reinterpret_cast<const float4*>(xr + 12);
        float vv[16] = {v0.x, v0.y, v0.z, v0.w, v1.x, v1.y, v1.z, v1.w,
                        v2.x, v2.y, v2.z, v2.w, v3.x, v3.y, v3.z, v3.w};
        ushort hb[16];
        float sq = 0.f;
#pragma unroll
        for (int e = 0; e < 16; ++e) {
            ushort h = f2bf(vv[e] * wq[e]);
            hb[e] = h;
            float xv = bf2f(h);
            sq = fmaf(xv, xv, sq);
        }
        char* xb = reinterpret_cast<char*>(sm.xt);
#pragma unroll
        for (int hh = 0; hh < 2; ++hh) {
            uint4 u = make_uint4(
                (unsigned)hb[hh * 8 + 0] | ((unsigned)hb[hh * 8 + 1] << 16),
                (unsigned)hb[hh * 8 + 2] | ((unsigned)hb[hh * 8 + 3] << 16),
                (unsigned)hb[hh * 8 + 4] | ((unsigned)hb[hh * 8 + 5] << 16),
                (unsigned)hb[hh * 8 + 6] | ((unsigned)hb[hh * 8 + 7] << 16));
            int sw = col * 128 + ((q * 32 + hh * 16) ^ ((col & 7) << 4));
            *reinterpret_cast<uint4*>(xb + sw) = u;
        }
        sq += __shfl_xor(sq, 1);
        sq += __shfl_xor(sq, 2);
        if (q == 0) sm.xs2[col] = sq * L2E;
    }

    // ---- z fragments: wave's 64 rows -> VGPRs (B-operand), + z2/al/zm ----
    short8 zf[4][2];
    float z2v[4], alv[4], zmv[4];
    {
        float wz[16];
#pragma unroll
        for (int h = 0; h < 2; ++h)
#pragma unroll
            for (int e = 0; e < 8; ++e)
                wz[h * 8 + e] = __expf(-0.5f * ls[h * 32 + g * 8 + e]);
#pragma unroll
        for (int t = 0; t < 4; ++t) {
            const int row = wave * 64 + t * 16 + p;
            const float* zr = z + (size_t)row * N_DESC;
            float4 v0 = *reinterpret_cast<const float4*>(zr + g * 8);
            float4 v1 = *reinterpret_cast<const float4*>(zr + g * 8 + 4);
            float4 v2 = *reinterpret_cast<const float4*>(zr + 32 + g * 8);
            float4 v3 = *reinterpret_cast<const float4*>(zr + 32 + g * 8 + 4);
            float vv[16] = {v0.x, v0.y, v0.z, v0.w, v1.x, v1.y, v1.z, v1.w,
                            v2.x, v2.y, v2.z, v2.w, v3.x, v3.y, v3.z, v3.w};
            float sq = 0.f;
            short8 bb[2];
#pragma unroll
            for (int h = 0; h < 2; ++h)
#pragma unroll
                for (int e = 0; e < 8; ++e) {
                    ushort hh = f2bf(vv[h * 8 + e] * wz[h * 8 + e]);
                    bb[h][e] = (short)hh;
                    float zv = bf2f(hh);
                    sq = fmaf(zv, zv, sq);
                }
            zf[t][0] = bb[0]; zf[t][1] = bb[1];
            sq += __shfl_xor(sq, 16);   // sum k-groups -> full ||zw||^2
            sq += __shfl_xor(sq, 32);
            z2v[t] = sq * L2E;
            alv[t] = alpha[row];
            float mn = z2v[t];
            mn = fminf(mn, __shfl_xor(mn, 1));
            mn = fminf(mn, __shfl_xor(mn, 2));
            mn = fminf(mn, __shfl_xor(mn, 4));
            mn = fminf(mn, __shfl_xor(mn, 8));
            zmv[t] = mn;   // (kept for reference; exact test below uses z2v)
        }
    }

    __syncthreads();   // x-panel + xs2 + colPart ready

    const char* xb = reinterpret_cast<const char*>(sm.xt);
    const int rb0 = p * 128 + ((16 * g)      ^ ((p & 7) << 4));
    const int rb1 = p * 128 + ((64 + 16 * g) ^ ((p & 7) << 4));

#pragma unroll 2
    for (int s = 0; s < STRIPS; ++s) {
        short8 a0 = *reinterpret_cast<const short8*>(xb + s * 2048 + rb0);
        short8 a1 = *reinterpret_cast<const short8*>(xb + s * 2048 + rb1);
        float4 xs4 = *reinterpret_cast<const float4*>(&sm.xs2[s * 16 + 4 * g]);

#pragma unroll
        for (int t = 0; t < 4; ++t) {
            f32x4 d = {0.f, 0.f, 0.f, 0.f};
            d = __builtin_amdgcn_mfma_f32_16x16x32_bf16(a0, zf[t][0], d, 0, 0, 0);
            d = __builtin_amdgcn_mfma_f32_16x16x32_bf16(a1, zf[t][1], d, 0, 0, 0);

            // exact per-lane args: arg_r = L2E2*d[r] - xs2[col r] - z2[row p]
            float m0 = fmaf(d[0], L2E2, -xs4.x);
            float m1 = fmaf(d[1], L2E2, -xs4.y);
            float m2 = fmaf(d[2], L2E2, -xs4.z);
            float m3 = fmaf(d[3], L2E2, -xs4.w);
            float m  = fmaxf(fmaxf(m0, m1), fmaxf(m2, m3)) - z2v[t];

            if (!__all(m < SKIP_THR)) {
                // rare path: real contribution somewhere in this 16x64 tile
                float v0 = alv[t] * __builtin_amdgcn_exp2f(m0 - z2v[t]);
                float v1 = alv[t] * __builtin_amdgcn_exp2f(m1 - z2v[t]);
                float v2 = alv[t] * __builtin_amdgcn_exp2f(m2 - z2v[t]);
                float v3 = alv[t] * __builtin_amdgcn_exp2f(m3 - z2v[t]);
#pragma unroll
                for (int bit = 1; bit < 16; bit <<= 1) {
                    v0 += __shfl_xor(v0, bit);
                    v1 += __shfl_xor(v1, bit);
                    v2 += __shfl_xor(v2, bit);
                    v3 += __shfl_xor(v3, bit);
                }
                if (p == 0) {
                    sm.colPart[wave][s * 16 + 4 * g + 0] += v0;
                    sm.colPart[wave][s * 16 + 4 * g + 1] += v1;
                    sm.colPart[wave][s * 16 + 4 * g + 2] += v2;
                    sm.colPart[wave][s * 16 + 4 * g + 3] += v3;
                }
            }
        }
    }

    __syncthreads();   // all colPart contributions visible

    // ---- final: out[jb + c] = sum over 16 wave slots ----
    if (tid < 256) {
        float r = 0.f;
#pragma unroll
        for (int w = 0; w < 16; ++w) r += sm.colPart[w][tid];
        out[jb + tid] = r;
    }
}

extern "C" void kernel_launch(void* const* d_in, const int* in_sizes, int n_in,
                              void* d_out, int out_size, void* d_ws, size_t ws_size,
                              hipStream_t stream) {
    const float* x     = (const float*)d_in[0];   // (65536, 64)
    const float* z     = (const float*)d_in[1];   // (1024, 64)
    const float* alpha = (const float*)d_in[2];   // (1024,)
    const float* ls    = (const float*)d_in[3];   // (64,)
    float* out = (float*)d_out;                   // (65536, 1)

    igpr_fused<<<dim3(N_X / 256), dim3(1024), 0, stream>>>(x, z, alpha, ls, out);
}